// Round 2
// baseline (17.362 us; speedup 1.0000x reference)
//
#include <hip/hip_runtime.h>

#define B_SZ  64
#define L_SZ  4096
#define VOCAB 33
#define D_SZ  256
#define NW    16      // waves per block (1024 threads)
#define KS    4       // k-split groups
#define KPG   64      // k per group (256/4)

__global__ __launch_bounds__(1024) void prot_net_fused(
    const int* __restrict__ X,
    const int* __restrict__ valid_lens,
    const float* __restrict__ emb,
    const float* __restrict__ W1,
    const float* __restrict__ b1,
    const float* __restrict__ W2,
    const float* __restrict__ b2,
    float* __restrict__ out)
{
    __shared__ int   s_cnt[NW][VOCAB];
    __shared__ float s_cntf[VOCAB];
    __shared__ float s_part[KS][D_SZ];
    __shared__ float s_vec[D_SZ];          // pooled, then h

    const int b   = blockIdx.x;
    const int tid = threadIdx.x;
    const int wv  = tid >> 6;              // wave id 0..15
    const int g   = tid >> 8;              // k-group 0..3
    const int d   = tid & (D_SZ - 1);      // feature 0..255

    // ---- pre-issue all data-independent loads: their latency hides
    // under the histogram phase ----
    float w1[KPG];
    #pragma unroll
    for (int j = 0; j < KPG; ++j)
        w1[j] = W1[(g * KPG + j) * D_SZ + d];

    // emb: group g covers v = g*8 .. g*8+7, plus v=32 handled by g==0
    float e[8];
    #pragma unroll
    for (int j = 0; j < 8; ++j)
        e[j] = emb[(g * 8 + j) * D_SZ + d];
    const float e32   = (g == 0) ? emb[32 * D_SZ + d] : 0.0f;
    const float bias1 = (tid < D_SZ) ? b1[tid] : 0.0f;
    const float bias2 = (tid < D_SZ) ? b2[tid] : 0.0f;
    const int   vl    = valid_lens[b];
    const int4  t     = reinterpret_cast<const int4*>(X + (size_t)b * L_SZ)[tid];

    // ---- per-wave privatized histogram ----
    if (tid < NW * VOCAB) ((int*)s_cnt)[tid] = 0;
    __syncthreads();

    const int l0 = tid * 4;
    if (l0 + 0 < vl) atomicAdd(&s_cnt[wv][t.x], 1);
    if (l0 + 1 < vl) atomicAdd(&s_cnt[wv][t.y], 1);
    if (l0 + 2 < vl) atomicAdd(&s_cnt[wv][t.z], 1);
    if (l0 + 3 < vl) atomicAdd(&s_cnt[wv][t.w], 1);
    __syncthreads();

    if (tid < VOCAB) {
        int c = 0;
        #pragma unroll
        for (int w = 0; w < NW; ++w) c += s_cnt[w][tid];
        s_cntf[tid] = (float)c;
    }
    __syncthreads();

    // ---- pooled[d] = sum_v cnt[v] * emb[v,d], 4-way split over v ----
    float p = 0.0f;
    #pragma unroll
    for (int j = 0; j < 8; ++j)
        p = fmaf(s_cntf[g * 8 + j], e[j], p);
    if (g == 0) p = fmaf(s_cntf[32], e32, p);
    s_part[g][d] = p;
    __syncthreads();

    if (tid < D_SZ)
        s_vec[tid] = s_part[0][tid] + s_part[1][tid] + s_part[2][tid] + s_part[3][tid];
    __syncthreads();

    // ---- layer 1: partial over k in [g*64, g*64+64) ----
    float acc = 0.0f;
    #pragma unroll
    for (int j = 0; j < KPG; ++j)
        acc = fmaf(s_vec[g * KPG + j], w1[j], acc);

    // issue W2 loads now (w1 regs are dead); latency hides under reduce
    float w2[KPG];
    #pragma unroll
    for (int j = 0; j < KPG; ++j)
        w2[j] = W2[(g * KPG + j) * D_SZ + d];

    s_part[g][d] = acc;
    __syncthreads();
    if (tid < D_SZ) {
        float h = bias1 + s_part[0][tid] + s_part[1][tid] + s_part[2][tid] + s_part[3][tid];
        s_vec[tid] = fmaxf(h, 0.0f);
    }
    __syncthreads();

    // ---- layer 2 ----
    float acc2 = 0.0f;
    #pragma unroll
    for (int j = 0; j < KPG; ++j)
        acc2 = fmaf(s_vec[g * KPG + j], w2[j], acc2);
    s_part[g][d] = acc2;
    __syncthreads();
    if (tid < D_SZ) {
        float o = bias2 + s_part[0][tid] + s_part[1][tid] + s_part[2][tid] + s_part[3][tid];
        out[(size_t)b * D_SZ + tid] = fmaxf(o, 0.0f);
    }
}

extern "C" void kernel_launch(void* const* d_in, const int* in_sizes, int n_in,
                              void* d_out, int out_size, void* d_ws, size_t ws_size,
                              hipStream_t stream) {
    const int*   X          = (const int*)d_in[0];
    const int*   valid_lens = (const int*)d_in[1];
    const float* emb        = (const float*)d_in[2];
    const float* W1         = (const float*)d_in[3];
    const float* b1         = (const float*)d_in[4];
    const float* W2         = (const float*)d_in[5];
    const float* b2         = (const float*)d_in[6];
    float* out = (float*)d_out;

    prot_net_fused<<<B_SZ, 1024, 0, stream>>>(X, valid_lens, emb, W1, b1, W2, b2, out);
}

// Round 3
// 12.083 us; speedup vs baseline: 1.4369x; 1.4369x over previous
//
#include <hip/hip_runtime.h>

#define B_SZ  64
#define L_SZ  4096
#define VOCAB 33
#define D_SZ  256
#define NT    512     // threads per block (8 waves)
#define NW    8       // waves per block
#define KS    2       // k-split groups
#define KPG   128     // k per group

__global__ __launch_bounds__(NT) void prot_net_fused(
    const int* __restrict__ X,
    const int* __restrict__ valid_lens,
    const float* __restrict__ emb,
    const float* __restrict__ W1,
    const float* __restrict__ b1,
    const float* __restrict__ W2,
    const float* __restrict__ b2,
    float* __restrict__ out)
{
    __shared__ int   s_cnt[NW][VOCAB];
    __shared__ float s_cntf[VOCAB];
    __shared__ float s_part[KS][D_SZ];
    __shared__ float s_vec[D_SZ];          // pooled, then h

    const int b   = blockIdx.x;
    const int tid = threadIdx.x;
    const int wv  = tid >> 6;              // wave id 0..7
    const int g   = tid >> 8;              // k/v group 0..1
    const int d   = tid & (D_SZ - 1);      // feature 0..255

    // ---- small-state prefetch (latency hides under histogram) ----
    // emb: group g covers v = g*16 .. g*16+15; v=32 folded in via e16 (0 for g=1)
    float e[16];
    #pragma unroll
    for (int j = 0; j < 16; ++j)
        e[j] = emb[(g * 16 + j) * D_SZ + d];
    const float e16   = (g == 0) ? emb[32 * D_SZ + d] : 0.0f;
    const float bias1 = (tid < D_SZ) ? b1[tid] : 0.0f;
    const float bias2 = (tid < D_SZ) ? b2[tid] : 0.0f;
    const int   vl    = valid_lens[b];
    const int4* xrow4 = reinterpret_cast<const int4*>(X + (size_t)b * L_SZ);
    const int4  t0    = xrow4[tid];
    const int4  t1    = xrow4[tid + NT];

    // ---- per-wave privatized histogram ----
    for (int i = tid; i < NW * VOCAB; i += NT) ((int*)s_cnt)[i] = 0;
    __syncthreads();

    const int l0 = tid * 4;
    const int l1 = (tid + NT) * 4;
    if (l0 + 0 < vl) atomicAdd(&s_cnt[wv][t0.x], 1);
    if (l0 + 1 < vl) atomicAdd(&s_cnt[wv][t0.y], 1);
    if (l0 + 2 < vl) atomicAdd(&s_cnt[wv][t0.z], 1);
    if (l0 + 3 < vl) atomicAdd(&s_cnt[wv][t0.w], 1);
    if (l1 + 0 < vl) atomicAdd(&s_cnt[wv][t1.x], 1);
    if (l1 + 1 < vl) atomicAdd(&s_cnt[wv][t1.y], 1);
    if (l1 + 2 < vl) atomicAdd(&s_cnt[wv][t1.z], 1);
    if (l1 + 3 < vl) atomicAdd(&s_cnt[wv][t1.w], 1);
    __syncthreads();

    if (tid < VOCAB) {
        int c = 0;
        #pragma unroll
        for (int w = 0; w < NW; ++w) c += s_cnt[w][tid];
        s_cntf[tid] = (float)c;
    }
    __syncthreads();

    // ---- pooled[d] = sum_v cnt[v] * emb[v,d], 2-way split over v ----
    float p = 0.0f;
    #pragma unroll
    for (int j = 0; j < 16; ++j)
        p = fmaf(s_cntf[g * 16 + j], e[j], p);
    p = fmaf(s_cntf[32], e16, p);          // adds 0 for g==1
    s_part[g][d] = p;
    __syncthreads();

    if (tid < D_SZ)
        s_vec[tid] = s_part[0][tid] + s_part[1][tid];
    __syncthreads();

    // ---- layer 1: partial over k in [g*128, g*128+128) ----
    float acc = 0.0f;
    #pragma unroll
    for (int j = 0; j < KPG; ++j) {
        int k = g * KPG + j;
        acc = fmaf(s_vec[k], W1[k * D_SZ + d], acc);
    }
    s_part[g][d] = acc;
    __syncthreads();
    if (tid < D_SZ) {
        float h = bias1 + s_part[0][tid] + s_part[1][tid];
        s_vec[tid] = fmaxf(h, 0.0f);
    }
    __syncthreads();

    // ---- layer 2 ----
    float acc2 = 0.0f;
    #pragma unroll
    for (int j = 0; j < KPG; ++j) {
        int k = g * KPG + j;
        acc2 = fmaf(s_vec[k], W2[k * D_SZ + d], acc2);
    }
    s_part[g][d] = acc2;
    __syncthreads();
    if (tid < D_SZ) {
        float o = bias2 + s_part[0][tid] + s_part[1][tid];
        out[(size_t)b * D_SZ + tid] = fmaxf(o, 0.0f);
    }
}

extern "C" void kernel_launch(void* const* d_in, const int* in_sizes, int n_in,
                              void* d_out, int out_size, void* d_ws, size_t ws_size,
                              hipStream_t stream) {
    const int*   X          = (const int*)d_in[0];
    const int*   valid_lens = (const int*)d_in[1];
    const float* emb        = (const float*)d_in[2];
    const float* W1         = (const float*)d_in[3];
    const float* b1         = (const float*)d_in[4];
    const float* W2         = (const float*)d_in[5];
    const float* b2         = (const float*)d_in[6];
    float* out = (float*)d_out;

    prot_net_fused<<<B_SZ, NT, 0, stream>>>(X, valid_lens, emb, W1, b1, W2, b2, out);
}

// Round 4
// 11.471 us; speedup vs baseline: 1.5136x; 1.0533x over previous
//
#include <hip/hip_runtime.h>

#define B_SZ  64
#define L_SZ  4096
#define VOCAB 33
#define D_SZ  256
#define NT    512    // threads per block (8 waves)
#define NW    8      // waves per block
#define G     8      // k-split groups (== wave id)
#define KPG   32     // k per group (256/8)
#define C     64     // float4 output columns (256/4)

__global__ __launch_bounds__(NT) void prot_net_fused(
    const int* __restrict__ X,
    const int* __restrict__ valid_lens,
    const float* __restrict__ emb,
    const float* __restrict__ W1,
    const float* __restrict__ b1,
    const float* __restrict__ W2,
    const float* __restrict__ b2,
    float* __restrict__ out)
{
    __shared__ int    s_cnt[NW][VOCAB];
    __shared__ float4 s_part[G][C];
    __shared__ float  s_vec[D_SZ];      // pooled, then h (scalar-indexable)

    const int b   = blockIdx.x;
    const int tid = threadIdx.x;
    const int g   = tid >> 6;           // wave id == k/v group, 0..7
    const int c   = tid & 63;           // float4 column, 0..63

    const float4* emb4 = reinterpret_cast<const float4*>(emb);
    const float4* W14  = reinterpret_cast<const float4*>(W1);
    const float4* W24  = reinterpret_cast<const float4*>(W2);

    // ---- prefetch small state; latency hides under histogram ----
    float4 e4[4];
    #pragma unroll
    for (int j = 0; j < 4; ++j)
        e4[j] = emb4[(g * 4 + j) * C + c];
    float4 e32 = make_float4(0.f, 0.f, 0.f, 0.f);
    if (g == 0) e32 = emb4[32 * C + c];

    float4 bias1 = make_float4(0.f, 0.f, 0.f, 0.f);
    float4 bias2 = make_float4(0.f, 0.f, 0.f, 0.f);
    if (tid < C) {
        bias1 = reinterpret_cast<const float4*>(b1)[tid];
        bias2 = reinterpret_cast<const float4*>(b2)[tid];
    }
    const int   vl    = valid_lens[b];
    const int4* xrow4 = reinterpret_cast<const int4*>(X + (size_t)b * L_SZ);
    const int4  t0    = xrow4[tid];
    const int4  t1    = xrow4[tid + NT];

    // ---- per-wave privatized histogram ----
    if (tid < NW * VOCAB) ((int*)s_cnt)[tid] = 0;
    __syncthreads();

    const int l0 = tid * 4;
    const int l1 = (tid + NT) * 4;
    if (l0 + 0 < vl) atomicAdd(&s_cnt[g][t0.x], 1);
    if (l0 + 1 < vl) atomicAdd(&s_cnt[g][t0.y], 1);
    if (l0 + 2 < vl) atomicAdd(&s_cnt[g][t0.z], 1);
    if (l0 + 3 < vl) atomicAdd(&s_cnt[g][t0.w], 1);
    if (l1 + 0 < vl) atomicAdd(&s_cnt[g][t1.x], 1);
    if (l1 + 1 < vl) atomicAdd(&s_cnt[g][t1.y], 1);
    if (l1 + 2 < vl) atomicAdd(&s_cnt[g][t1.z], 1);
    if (l1 + 3 < vl) atomicAdd(&s_cnt[g][t1.w], 1);
    __syncthreads();

    // ---- per-thread count gather (LDS broadcast reads, no extra phase) ----
    float cf[4];
    #pragma unroll
    for (int j = 0; j < 4; ++j) {
        int s = 0;
        #pragma unroll
        for (int w = 0; w < NW; ++w) s += s_cnt[w][g * 4 + j];
        cf[j] = (float)s;
    }
    float c32 = 0.f;
    if (g == 0) {
        int s = 0;
        #pragma unroll
        for (int w = 0; w < NW; ++w) s += s_cnt[w][32];
        c32 = (float)s;
    }

    // ---- pooled partial: p4 = sum over this group's vocab slice ----
    float4 p = make_float4(0.f, 0.f, 0.f, 0.f);
    #pragma unroll
    for (int j = 0; j < 4; ++j) {
        p.x = fmaf(cf[j], e4[j].x, p.x);
        p.y = fmaf(cf[j], e4[j].y, p.y);
        p.z = fmaf(cf[j], e4[j].z, p.z);
        p.w = fmaf(cf[j], e4[j].w, p.w);
    }
    p.x = fmaf(c32, e32.x, p.x);
    p.y = fmaf(c32, e32.y, p.y);
    p.z = fmaf(c32, e32.z, p.z);
    p.w = fmaf(c32, e32.w, p.w);
    s_part[g][c] = p;
    __syncthreads();

    if (tid < C) {
        float4 s = s_part[0][tid];
        #pragma unroll
        for (int g2 = 1; g2 < G; ++g2) {
            float4 q = s_part[g2][tid];
            s.x += q.x; s.y += q.y; s.z += q.z; s.w += q.w;
        }
        reinterpret_cast<float4*>(s_vec)[tid] = s;
    }
    __syncthreads();

    // ---- layer 1: partial over k in [g*32, g*32+32), float4 weight loads ----
    float4 acc = make_float4(0.f, 0.f, 0.f, 0.f);
    #pragma unroll
    for (int j = 0; j < KPG; ++j) {
        int k = g * KPG + j;
        float  sv = s_vec[k];
        float4 w  = W14[k * C + c];
        acc.x = fmaf(sv, w.x, acc.x);
        acc.y = fmaf(sv, w.y, acc.y);
        acc.z = fmaf(sv, w.z, acc.z);
        acc.w = fmaf(sv, w.w, acc.w);
    }
    s_part[g][c] = acc;
    __syncthreads();

    if (tid < C) {
        float4 h = bias1;
        #pragma unroll
        for (int g2 = 0; g2 < G; ++g2) {
            float4 q = s_part[g2][tid];
            h.x += q.x; h.y += q.y; h.z += q.z; h.w += q.w;
        }
        h.x = fmaxf(h.x, 0.f); h.y = fmaxf(h.y, 0.f);
        h.z = fmaxf(h.z, 0.f); h.w = fmaxf(h.w, 0.f);
        reinterpret_cast<float4*>(s_vec)[tid] = h;
    }
    __syncthreads();

    // ---- layer 2 ----
    float4 acc2 = make_float4(0.f, 0.f, 0.f, 0.f);
    #pragma unroll
    for (int j = 0; j < KPG; ++j) {
        int k = g * KPG + j;
        float  sv = s_vec[k];
        float4 w  = W24[k * C + c];
        acc2.x = fmaf(sv, w.x, acc2.x);
        acc2.y = fmaf(sv, w.y, acc2.y);
        acc2.z = fmaf(sv, w.z, acc2.z);
        acc2.w = fmaf(sv, w.w, acc2.w);
    }
    s_part[g][c] = acc2;
    __syncthreads();

    if (tid < C) {
        float4 o = bias2;
        #pragma unroll
        for (int g2 = 0; g2 < G; ++g2) {
            float4 q = s_part[g2][tid];
            o.x += q.x; o.y += q.y; o.z += q.z; o.w += q.w;
        }
        o.x = fmaxf(o.x, 0.f); o.y = fmaxf(o.y, 0.f);
        o.z = fmaxf(o.z, 0.f); o.w = fmaxf(o.w, 0.f);
        reinterpret_cast<float4*>(out + (size_t)b * D_SZ)[tid] = o;
    }
}

extern "C" void kernel_launch(void* const* d_in, const int* in_sizes, int n_in,
                              void* d_out, int out_size, void* d_ws, size_t ws_size,
                              hipStream_t stream) {
    const int*   X          = (const int*)d_in[0];
    const int*   valid_lens = (const int*)d_in[1];
    const float* emb        = (const float*)d_in[2];
    const float* W1         = (const float*)d_in[3];
    const float* b1         = (const float*)d_in[4];
    const float* W2         = (const float*)d_in[5];
    const float* b2         = (const float*)d_in[6];
    float* out = (float*)d_out;

    prot_net_fused<<<B_SZ, NT, 0, stream>>>(X, valid_lens, emb, W1, b1, W2, b2, out);
}